// Round 1
// baseline (7459.137 us; speedup 1.0000x reference)
//
#include <hip/hip_runtime.h>
#include <stdint.h>

#define H 512
#define B_SZ 1024
#define T_WARM 256
#define NSTEPS 64
#define RPB 16                 // rows per block
#define NBLK (B_SZ / RPB)      // 64 blocks
#define NTHR 512               // 8 waves
#define HSTR 520               // LDS row stride (ushorts): 16B-aligned, breaks pow2 bank pattern

typedef __attribute__((ext_vector_type(8))) short bf16x8;
typedef __attribute__((ext_vector_type(4))) float f32x4;

__device__ __forceinline__ ushort f2bf(float f) {
    uint32_t u = __builtin_bit_cast(uint32_t, f);
    u += 0x7FFFu + ((u >> 16) & 1u);   // round-to-nearest-even
    return (ushort)(u >> 16);
}
__device__ __forceinline__ float bf2f(ushort h) {
    uint32_t u = ((uint32_t)h) << 16;
    return __builtin_bit_cast(float, u);
}

// Split W_hh (fp32, row-major [j][k], used as h @ W^T) into bf16 hi/lo pair; bias = b_ih + b_hh.
__global__ void prep_kernel(const float* __restrict__ W_hh,
                            const float* __restrict__ b_ih,
                            const float* __restrict__ b_hh,
                            ushort* __restrict__ Wh, ushort* __restrict__ Wl,
                            float* __restrict__ bias) {
    int i = blockIdx.x * 256 + threadIdx.x;
    if (i < H * H) {
        float w = W_hh[i];
        ushort hi = f2bf(w);
        float rem = w - bf2f(hi);      // exact (Sterbenz-close)
        Wh[i] = hi;
        Wl[i] = f2bf(rem);
    }
    if (i < H) bias[i] = b_ih[i] + b_hh[i];
}

// One block = 16 batch rows for all 320 steps. h kept in LDS as bf16 hi/lo (ping-pong).
// Per step: D(16x512) = A(h,16x512) @ B(W^T,512x512) via mfma_f32_16x16x32_bf16, 3 hi/lo terms.
__launch_bounds__(NTHR, 1)
__global__ void rnn_kernel(const float* __restrict__ x,      // (B,T) row-major
                           const float* __restrict__ W_ih,   // (H,1) -> flat H (w_in)
                           const float* __restrict__ b_fc_p, // scalar
                           const float* __restrict__ W_fc,   // (1,H) -> flat H
                           const ushort* __restrict__ Wh,
                           const ushort* __restrict__ Wl,
                           const float* __restrict__ bias_g,
                           float* __restrict__ out) {        // (B, NSTEPS)
    __shared__ ushort h_hi[2][RPB * HSTR];
    __shared__ ushort h_lo[2][RPB * HSTR];
    __shared__ float lx[RPB * T_WARM];   // this block's x slice, 16 KB
    __shared__ float w_in_s[H];
    __shared__ float bias_s[H];
    __shared__ float w_fc_s[H];
    __shared__ float sy[RPB];

    const int tid = threadIdx.x;
    const int row0 = blockIdx.x * RPB;

    // preload x slice (contiguous 16x256 fp32), params, zero h buffer 0
    for (int i = tid; i < RPB * T_WARM; i += NTHR) lx[i] = x[row0 * T_WARM + i];
    for (int i = tid; i < H; i += NTHR) {
        w_in_s[i] = W_ih[i];
        bias_s[i] = bias_g[i];
        w_fc_s[i] = W_fc[i];
    }
    for (int i = tid; i < RPB * HSTR; i += NTHR) { h_hi[0][i] = 0; h_lo[0][i] = 0; }
    const float bfc = b_fc_p[0];
    __syncthreads();

    const int lane = tid & 63;
    const int wave = tid >> 6;
    const int n = lane & 15;   // A-row (batch m for A), B-col (j) within tile
    const int q = lane >> 4;   // quad
    const int j0 = wave * 64;  // this wave owns output cols j0..j0+63 (4 tiles of 16)

    int cur = 0;
    for (int t = 0; t < T_WARM + NSTEPS; ++t) {
        if (t >= T_WARM) {
            // rollout: y_r = dot(h_r, w_fc) + b_fc from current h; emit + stash for matmul input
            const int r = tid >> 5, l32 = tid & 31;
            const ushort* hh = &h_hi[cur][r * HSTR];
            const ushort* hl = &h_lo[cur][r * HSTR];
            float s = 0.f;
            #pragma unroll
            for (int p = 0; p < H / 32; ++p) {
                int k = l32 + p * 32;
                s += (bf2f(hh[k]) + bf2f(hl[k])) * w_fc_s[k];
            }
            #pragma unroll
            for (int off = 16; off > 0; off >>= 1) s += __shfl_down(s, off, 32);
            if (l32 == 0) {
                float y = s + bfc;
                sy[r] = y;
                out[(row0 + r) * NSTEPS + (t - T_WARM)] = y;
            }
            __syncthreads();
        }

        // K-loop: acc[c] += h_tile @ W^T_tile  (3 hi/lo terms)
        f32x4 acc[4];
        #pragma unroll
        for (int c = 0; c < 4; ++c) acc[c] = (f32x4){0.f, 0.f, 0.f, 0.f};

        const ushort* ha = &h_hi[cur][n * HSTR];
        const ushort* la = &h_lo[cur][n * HSTR];
        #pragma unroll
        for (int kt = 0; kt < H / 32; ++kt) {
            const int kb = kt * 32 + q * 8;
            bf16x8 a_hi = *(const bf16x8*)(ha + kb);
            bf16x8 a_lo = *(const bf16x8*)(la + kb);
            #pragma unroll
            for (int c = 0; c < 4; ++c) {
                const int j = j0 + c * 16 + n;
                bf16x8 b_hi = *(const bf16x8*)(Wh + j * H + kb);
                bf16x8 b_lo = *(const bf16x8*)(Wl + j * H + kb);
                acc[c] = __builtin_amdgcn_mfma_f32_16x16x32_bf16(a_hi, b_hi, acc[c], 0, 0, 0);
                acc[c] = __builtin_amdgcn_mfma_f32_16x16x32_bf16(a_lo, b_hi, acc[c], 0, 0, 0);
                acc[c] = __builtin_amdgcn_mfma_f32_16x16x32_bf16(a_hi, b_lo, acc[c], 0, 0, 0);
            }
        }

        // epilogue: preact = acc + s_m*w_in[j] + bias[j]; relu; split to bf16 hi/lo; write next buf
        const int nxt = cur ^ 1;
        #pragma unroll
        for (int c = 0; c < 4; ++c) {
            const int j = j0 + c * 16 + n;
            const float wi = w_in_s[j];
            const float bj = bias_s[j];
            #pragma unroll
            for (int i = 0; i < 4; ++i) {
                const int m = q * 4 + i;           // C/D: row = quad*4 + reg, col = lane&15
                const float s = (t < T_WARM) ? lx[m * T_WARM + t] : sy[m];
                float v = acc[c][i] + s * wi + bj;
                v = fmaxf(v, 0.f);
                ushort hi = f2bf(v);
                float rem = v - bf2f(hi);
                h_hi[nxt][m * HSTR + j] = hi;
                h_lo[nxt][m * HSTR + j] = f2bf(rem);
            }
        }
        __syncthreads();
        cur = nxt;
    }
}

extern "C" void kernel_launch(void* const* d_in, const int* in_sizes, int n_in,
                              void* d_out, int out_size, void* d_ws, size_t ws_size,
                              hipStream_t stream) {
    const float* x    = (const float*)d_in[0];
    const float* W_ih = (const float*)d_in[1];
    const float* W_hh = (const float*)d_in[2];
    const float* b_ih = (const float*)d_in[3];
    const float* b_hh = (const float*)d_in[4];
    const float* W_fc = (const float*)d_in[5];
    const float* b_fc = (const float*)d_in[6];
    float* out = (float*)d_out;

    // workspace carve: Wh (512KB) | Wl (512KB) | bias (2KB)
    ushort* Wh = (ushort*)d_ws;
    ushort* Wl = Wh + H * H;
    float* bias = (float*)(Wl + H * H);

    prep_kernel<<<(H * H + 255) / 256, 256, 0, stream>>>(W_hh, b_ih, b_hh, Wh, Wl, bias);
    rnn_kernel<<<NBLK, NTHR, 0, stream>>>(x, W_ih, b_fc, W_fc, Wh, Wl, bias, out);
}